// Round 7
// baseline (1359.886 us; speedup 1.0000x reference)
//
#include <hip/hip_runtime.h>
#include <hip/hip_bf16.h>

#define BB 128
#define BPB 4
#define NBLK 32
#define SS 32
#define NSTEP 31
#define IND 32
#define HID 128
#define HID2 256
#define BSTR 272
#define ZSTR 136

typedef unsigned short u16;
typedef unsigned int u32;
typedef _Float16 f16;
typedef f16 h2 __attribute__((ext_vector_type(2)));
typedef __fp16 fp16v2 __attribute__((ext_vector_type(2)));
typedef _Float16 f16x8 __attribute__((ext_vector_type(8)));
typedef float f32x4 __attribute__((ext_vector_type(4)));

__device__ __forceinline__ float dot2f(u32 a, u32 b, float c){
#if __has_builtin(__builtin_amdgcn_fdot2)
  h2 ha, hb; __builtin_memcpy(&ha, &a, 4); __builtin_memcpy(&hb, &b, 4);
  return __builtin_amdgcn_fdot2(ha, hb, c, false);
#else
  h2 ha, hb; __builtin_memcpy(&ha, &a, 4); __builtin_memcpy(&hb, &b, 4);
  return c + (float)ha[0]*(float)hb[0] + (float)ha[1]*(float)hb[1];
#endif
}
__device__ __forceinline__ u32 pkh2(float a, float b){
  fp16v2 r = __builtin_amdgcn_cvt_pkrtz(a, b);
  u32 u; __builtin_memcpy(&u, &r, 4); return u;
}
__device__ __forceinline__ u16 f2h(float f){ f16 h = (f16)f; u16 u; __builtin_memcpy(&u, &h, 2); return u; }
__device__ __forceinline__ float gelu_f(float x){ return 0.5f * x * (1.0f + erff(x * 0.70710678118654752440f)); }

// 4-step DPP sum within each 16-lane row; lane (15 mod 16) holds the 16-sum
__device__ __forceinline__ float dpp16sum(float v){
  int iv; float tf;
  #define DPPADD(CTRL) \
    __builtin_memcpy(&iv, &v, 4); \
    iv = __builtin_amdgcn_update_dpp(0, iv, CTRL, 0xf, 0xf, true); \
    __builtin_memcpy(&tf, &iv, 4); \
    v += tf;
  DPPADD(0x111) DPPADD(0x112) DPPADD(0x114) DPPADD(0x118)
  #undef DPPADD
  return v;
}

// ---------------- prep: dxh (packed half2 dX), hb, gb ----------------
__global__ __launch_bounds__(128) void prep_misc(const float* __restrict__ path,
                                                 const float* __restrict__ ts,
                                                 const float* __restrict__ b3,
                                                 u32* __restrict__ dxh,
                                                 float* __restrict__ hb,
                                                 float* __restrict__ gb){
  const int b = blockIdx.x, tid = threadIdx.x;
  __shared__ float sdx[NSTEP * IND];
  for (int t = tid; t < NSTEP * IND; t += 128){
    int s = t >> 5, i = t & 31;
    float dt = ts[b*SS + s + 1] - ts[b*SS + s];
    sdx[t] = (path[(b*SS + s + 1)*IND + i] - path[(b*SS + s)*IND + i]) / dt;
  }
  if (tid < NSTEP) hb[b*NSTEP + tid] = ts[b*SS + tid + 1] - ts[b*SS + tid];
  __syncthreads();
  for (int t = tid; t < NSTEP * 16; t += 128){
    int s = t >> 4, i2 = t & 15;
    dxh[((size_t)b*NSTEP + s)*16 + i2] = pkh2(sdx[s*IND + 2*i2], sdx[s*IND + 2*i2 + 1]);
  }
  if (tid < HID){
    float w[IND];
    #pragma unroll
    for (int i = 0; i < IND; ++i) w[i] = b3[tid*IND + i];
    for (int s = 0; s < NSTEP; ++s){
      float a = 0.f;
      #pragma unroll
      for (int i = 0; i < IND; ++i) a = fmaf(w[i], sdx[s*IND + i], a);
      gb[(b*NSTEP + s)*HID + tid] = a;
    }
  }
}

// ---------------- pack vf_W3 (fp32) -> half2 pairs over i ----------------
__global__ __launch_bounds__(256) void pack_w3(const float* __restrict__ W3, u32* __restrict__ w3h){
  int i = blockIdx.x*256 + threadIdx.x;
  if (i < (HID2*HID*IND)/2) w3h[i] = pkh2(W3[2*i], W3[2*i + 1]);
}

// ---------------- pack W1/W2 (and enc W1/W2) into MFMA B-fragment order ----------------
__global__ __launch_bounds__(256) void pack_wf(const float* __restrict__ W1,
                                               const float* __restrict__ W2,
                                               const float* __restrict__ EW1,
                                               const float* __restrict__ EW2,
                                               u32* __restrict__ w1f,
                                               u32* __restrict__ w2f,
                                               u32* __restrict__ w1e,
                                               u32* __restrict__ w2e){
  int i = blockIdx.x*256 + threadIdx.x;
  if (i < 16384){
    int lane_blk = i >> 6, rem = i & 63;
    int i16 = rem >> 2, q = rem & 3;
    int w = lane_blk >> 6, lane = lane_blk & 63;
    int kt = i16 >> 2, nt = i16 & 3;
    int k = kt*32 + (lane >> 4)*8 + 2*q;
    int col = w*64 + nt*16 + (lane & 15);
    w1f[i] = pkh2(W1[(size_t)k*HID2 + col], W1[(size_t)(k+1)*HID2 + col]);
  } else if (i < 49152){
    int j = i - 16384;
    int lane_blk = j >> 7, rem = j & 127;
    int i32i = rem >> 2, q = rem & 3;
    int w = lane_blk >> 6, lane = lane_blk & 63;
    int kt = i32i >> 2, nt = i32i & 3;
    int k = kt*32 + (lane >> 4)*8 + 2*q;
    int col = w*64 + nt*16 + (lane & 15);
    w2f[j] = pkh2(W2[(size_t)k*HID2 + col], W2[(size_t)(k+1)*HID2 + col]);
  } else if (i < 51200){
    int u = i - 49152;
    int q = u & 3, nf = (u>>2) & 1, lane = (u>>3) & 63, w = u >> 9;
    int k = (lane >> 4)*8 + 2*q;
    int col = w*32 + nf*16 + (lane & 15);
    w1e[u] = pkh2(EW1[(size_t)k*HID + col], EW1[(size_t)(k+1)*HID + col]);
  } else if (i < 59392){
    int u = i - 51200;
    int q = u & 3, nf = (u>>2) & 1, kt = (u>>3) & 3, lane = (u>>5) & 63, w = u >> 11;
    int k = kt*32 + (lane >> 4)*8 + 2*q;
    int col = w*32 + nf*16 + (lane & 15);
    w2e[u] = pkh2(EW2[(size_t)k*HID + col], EW2[(size_t)(k+1)*HID + col]);
  }
}

// ---------------- G in B-fragment layout, coalesced stores ----------------
// per (sl,bb): Gp[o], o = (kt*8+nf)*256 + lane*4 + q  — thread id == o (coalesced)
//   u32 = pack(G[k0][h], G[k0+1][h]), k0 = kt*32+(lane>>4)*8+2q, h = nf*16+(lane&15)
__global__ __launch_bounds__(256) void gprep_h(const u32* __restrict__ w3h,
                                               const u32* __restrict__ dxh,
                                               u32* __restrict__ Gp, int s0){
  const int tid = threadIdx.x;
  const int sl = blockIdx.y; const int s = s0 + sl;
  const int o = blockIdx.x*256 + tid;
  const int q = o & 3, lane = (o>>2) & 63, nf = (o>>8) & 7, kt = o >> 11;
  const int k0 = kt*32 + (lane >> 4)*8 + 2*q;
  const int h = nf*16 + (lane & 15);
  const uint4* wa = (const uint4*)(w3h + ((size_t)k0*HID + h)*16);
  const uint4* wb = (const uint4*)(w3h + ((size_t)(k0+1)*HID + h)*16);
  uint4 A0 = wa[0], A1 = wa[1], A2 = wa[2], A3 = wa[3];
  uint4 B0 = wb[0], B1 = wb[1], B2 = wb[2], B3 = wb[3];
  __shared__ u32 sdx[BB * 16];
  for (int t = tid; t < BB * 16; t += 256){
    int bb = t >> 4, i2 = t & 15;
    sdx[t] = dxh[((size_t)bb*NSTEP + s)*16 + i2];
  }
  __syncthreads();
  const size_t base_sl = (size_t)sl * BB * 16384;
  for (int bb = 0; bb < BB; ++bb){
    const uint4* dp = (const uint4*)&sdx[bb*16];
    uint4 D0 = dp[0], D1 = dp[1], D2 = dp[2], D3 = dp[3];
    float g0 = 0.f, g1 = 0.f, g2 = 0.f, g3 = 0.f;
    g0 = dot2f(D0.x, A0.x, g0); g0 = dot2f(D0.y, A0.y, g0);
    g0 = dot2f(D0.z, A0.z, g0); g0 = dot2f(D0.w, A0.w, g0);
    g2 = dot2f(D1.x, A1.x, g2); g2 = dot2f(D1.y, A1.y, g2);
    g2 = dot2f(D1.z, A1.z, g2); g2 = dot2f(D1.w, A1.w, g2);
    g0 = dot2f(D2.x, A2.x, g0); g0 = dot2f(D2.y, A2.y, g0);
    g0 = dot2f(D2.z, A2.z, g0); g0 = dot2f(D2.w, A2.w, g0);
    g2 = dot2f(D3.x, A3.x, g2); g2 = dot2f(D3.y, A3.y, g2);
    g2 = dot2f(D3.z, A3.z, g2); g2 = dot2f(D3.w, A3.w, g2);
    g1 = dot2f(D0.x, B0.x, g1); g1 = dot2f(D0.y, B0.y, g1);
    g1 = dot2f(D0.z, B0.z, g1); g1 = dot2f(D0.w, B0.w, g1);
    g3 = dot2f(D1.x, B1.x, g3); g3 = dot2f(D1.y, B1.y, g3);
    g3 = dot2f(D1.z, B1.z, g3); g3 = dot2f(D1.w, B1.w, g3);
    g1 = dot2f(D2.x, B2.x, g1); g1 = dot2f(D2.y, B2.y, g1);
    g1 = dot2f(D2.z, B2.z, g1); g1 = dot2f(D2.w, B2.w, g1);
    g3 = dot2f(D3.x, B3.x, g3); g3 = dot2f(D3.y, B3.y, g3);
    g3 = dot2f(D3.z, B3.z, g3); g3 = dot2f(D3.w, B3.w, g3);
    Gp[base_sl + (size_t)bb*16384 + o] = pkh2(g0 + g2, g1 + g3);
  }
}

// ---------------- RK4 scan: 4 batch elements per block (MFMA M-rows) ----------------
struct ScanP {
  const float *path;
  const u32 *w1e, *w2e;
  const float *eb1,*eg1,*ebt1,*eb2,*eg2,*ebt2;
  const u32 *w1f, *w2f;
  const float *b1,*g1,*bt1,*b2,*g2,*bt2;
  const float *Wv,*bv,*Wo,*bo,*dW1,*db1,*dW2,*db2;
  const float *hb,*gb;
  const u32 *Gp;
  float *zstate, *out;
  int s0, s1, do_enc, do_epi;
};

__global__ __launch_bounds__(256, 1) void scan_kernel(ScanP p){
  const int tid = threadIdx.x;
  const int b0 = blockIdx.x * BPB;
  const int lane = tid & 63, w = tid >> 6;
  const int quad = lane >> 4, n16 = lane & 15, bl = n16 & 3;
  const bool owner = (quad == 0);

  __shared__ __align__(16) u16 bufA[BPB*BSTR];
  __shared__ __align__(16) u16 bufB[BPB*BSTR];
  __shared__ __align__(16) u16 zsth[BPB*ZSTR];
  __shared__ __align__(16) float redl[32];
  __shared__ __align__(16) float zf[BPB*HID];
  __shared__ __align__(16) float e1[HID];
  __shared__ __align__(16) float e2[HID];

  // persistent weight B-fragments (192 VGPRs)
  uint4 w1r[16], w2r[32];
  {
    const uint4* s1p = (const uint4*)p.w1f + ((size_t)(w*64 + lane))*16;
    #pragma unroll
    for (int i = 0; i < 16; ++i) w1r[i] = s1p[i];
    const uint4* s2p = (const uint4*)p.w2f + ((size_t)(w*64 + lane))*32;
    #pragma unroll
    for (int i = 0; i < 32; ++i) w2r[i] = s2p[i];
  }
  float rb1[4], rg1[4], rbt1[4], rb2[4], rg2[4], rbt2[4];
  #pragma unroll
  for (int nf = 0; nf < 4; ++nf){
    int col = w*64 + nf*16 + n16;
    rb1[nf] = p.b1[col]; rg1[nf] = p.g1[col]; rbt1[nf] = p.bt1[col];
    rb2[nf] = p.b2[col]; rg2[nf] = p.g2[col]; rbt2[nf] = p.bt2[col];
  }

  float zc[8];

  if (p.do_enc){
    // ---- encoder, MFMA M=4 ----
    uint4 e1r[2], e2r[8];
    {
      const uint4* q1 = (const uint4*)p.w1e + ((size_t)(w*64 + lane))*2;
      e1r[0] = q1[0]; e1r[1] = q1[1];
      const uint4* q2 = (const uint4*)p.w2e + ((size_t)(w*64 + lane))*8;
      #pragma unroll
      for (int i = 0; i < 8; ++i) e2r[i] = q2[i];
    }
    float ec1b[2],ec1g[2],ec1t[2],ec2b[2],ec2g[2],ec2t[2];
    #pragma unroll
    for (int nf = 0; nf < 2; ++nf){
      int colE = w*32 + nf*16 + n16;
      ec1b[nf]=p.eb1[colE]; ec1g[nf]=p.eg1[colE]; ec1t[nf]=p.ebt1[colE];
      ec2b[nf]=p.eb2[colE]; ec2g[nf]=p.eg2[colE]; ec2t[nf]=p.ebt2[colE];
    }
    f16x8 ax;
    {
      const float4* xp = (const float4*)(p.path + ((size_t)(b0+bl)*SS)*IND + quad*8);
      float4 xa = xp[0], xb = xp[1];
      u32 pk4[4] = { pkh2(xa.x,xa.y), pkh2(xa.z,xa.w), pkh2(xb.x,xb.y), pkh2(xb.z,xb.w) };
      __builtin_memcpy(&ax, pk4, 16);
    }
    f32x4 D0={0,0,0,0}, D1={0,0,0,0};
    { f16x8 bf;
      __builtin_memcpy(&bf, &e1r[0], 16); D0 = __builtin_amdgcn_mfma_f32_16x16x32_f16(ax, bf, D0, 0, 0, 0);
      __builtin_memcpy(&bf, &e1r[1], 16); D1 = __builtin_amdgcn_mfma_f32_16x16x32_f16(ax, bf, D1, 0, 0, 0); }
    float v0[2][4];
    #pragma unroll
    for (int i = 0; i < 4; ++i){ v0[0][i] = D0[i] + ec1b[0]; v0[1][i] = D1[i] + ec1b[1]; }
    {
      float sm[4], sqv[4];
      #pragma unroll
      for (int i = 0; i < 4; ++i){
        sm[i]  = dpp16sum(v0[0][i] + v0[1][i]);
        sqv[i] = dpp16sum(v0[0][i]*v0[0][i] + v0[1][i]*v0[1][i]);
      }
      if (lane == 15){
        ((float4*)redl)[w*2]   = make_float4(sm[0], sqv[0], sm[1], sqv[1]);
        ((float4*)redl)[w*2+1] = make_float4(sm[2], sqv[2], sm[3], sqv[3]);
      }
      __syncthreads();
      const float4* r4 = (const float4*)redl;
      float4 r0=r4[0], r1=r4[1], r2=r4[2], r3=r4[3], r5=r4[4], r6=r4[5], r7=r4[6], r8=r4[7];
      float ms[4], rs[4];
      ms[0]=((r0.x+r2.x)+(r5.x+r7.x))*(1.f/HID); float q0=((r0.y+r2.y)+(r5.y+r7.y))*(1.f/HID);
      ms[1]=((r0.z+r2.z)+(r5.z+r7.z))*(1.f/HID); float q1=((r0.w+r2.w)+(r5.w+r7.w))*(1.f/HID);
      ms[2]=((r1.x+r3.x)+(r6.x+r8.x))*(1.f/HID); float q2=((r1.y+r3.y)+(r6.y+r8.y))*(1.f/HID);
      ms[3]=((r1.z+r3.z)+(r6.z+r8.z))*(1.f/HID); float q3=((r1.w+r3.w)+(r6.w+r8.w))*(1.f/HID);
      rs[0]=rsqrtf(q0-ms[0]*ms[0]+1e-5f); rs[1]=rsqrtf(q1-ms[1]*ms[1]+1e-5f);
      rs[2]=rsqrtf(q2-ms[2]*ms[2]+1e-5f); rs[3]=rsqrtf(q3-ms[3]*ms[3]+1e-5f);
      if (owner){
        #pragma unroll
        for (int nf = 0; nf < 2; ++nf)
          #pragma unroll
          for (int i = 0; i < 4; ++i)
            zsth[i*ZSTR + w*32 + nf*16 + n16] = f2h(gelu_f((v0[nf][i]-ms[i])*rs[i]*ec1g[nf] + ec1t[nf]));
      }
    }
    __syncthreads();
    // enc layer2: K=128
    f32x4 E0={0,0,0,0}, E1={0,0,0,0};
    #pragma unroll
    for (int kt = 0; kt < 4; ++kt){
      f16x8 a; uint4 av = ((const uint4*)zsth)[bl*17 + kt*4 + quad]; __builtin_memcpy(&a, &av, 16);
      f16x8 bf;
      __builtin_memcpy(&bf, &e2r[kt*2+0], 16); E0 = __builtin_amdgcn_mfma_f32_16x16x32_f16(a, bf, E0, 0, 0, 0);
      __builtin_memcpy(&bf, &e2r[kt*2+1], 16); E1 = __builtin_amdgcn_mfma_f32_16x16x32_f16(a, bf, E1, 0, 0, 0);
    }
    #pragma unroll
    for (int i = 0; i < 4; ++i){ v0[0][i] = E0[i] + ec2b[0]; v0[1][i] = E1[i] + ec2b[1]; }
    {
      float sm[4], sqv[4];
      #pragma unroll
      for (int i = 0; i < 4; ++i){
        sm[i]  = dpp16sum(v0[0][i] + v0[1][i]);
        sqv[i] = dpp16sum(v0[0][i]*v0[0][i] + v0[1][i]*v0[1][i]);
      }
      if (lane == 15){
        ((float4*)redl)[w*2]   = make_float4(sm[0], sqv[0], sm[1], sqv[1]);
        ((float4*)redl)[w*2+1] = make_float4(sm[2], sqv[2], sm[3], sqv[3]);
      }
      __syncthreads();
      const float4* r4 = (const float4*)redl;
      float4 r0=r4[0], r1=r4[1], r2=r4[2], r3=r4[3], r5=r4[4], r6=r4[5], r7=r4[6], r8=r4[7];
      float ms[4], rs[4];
      ms[0]=((r0.x+r2.x)+(r5.x+r7.x))*(1.f/HID); float q0=((r0.y+r2.y)+(r5.y+r7.y))*(1.f/HID);
      ms[1]=((r0.z+r2.z)+(r5.z+r7.z))*(1.f/HID); float q1=((r0.w+r2.w)+(r5.w+r7.w))*(1.f/HID);
      ms[2]=((r1.x+r3.x)+(r6.x+r8.x))*(1.f/HID); float q2=((r1.y+r3.y)+(r6.y+r8.y))*(1.f/HID);
      ms[3]=((r1.z+r3.z)+(r6.z+r8.z))*(1.f/HID); float q3=((r1.w+r3.w)+(r6.w+r8.w))*(1.f/HID);
      rs[0]=rsqrtf(q0-ms[0]*ms[0]+1e-5f); rs[1]=rsqrtf(q1-ms[1]*ms[1]+1e-5f);
      rs[2]=rsqrtf(q2-ms[2]*ms[2]+1e-5f); rs[3]=rsqrtf(q3-ms[3]*ms[3]+1e-5f);
      if (owner){
        #pragma unroll
        for (int nf = 0; nf < 2; ++nf)
          #pragma unroll
          for (int i = 0; i < 4; ++i)
            zf[i*HID + w*32 + nf*16 + n16] = (v0[nf][i]-ms[i])*rs[i]*ec2g[nf] + ec2t[nf];
      }
    }
    __syncthreads();
    #pragma unroll
    for (int nf = 0; nf < 8; ++nf) zc[nf] = zf[w*HID + nf*16 + n16];
  } else {
    #pragma unroll
    for (int nf = 0; nf < 8; ++nf) zc[nf] = p.zstate[(size_t)(b0+w)*HID + nf*16 + n16];
  }

  const int nsteps = p.s1 - p.s0;
  #pragma unroll 1
  for (int sl = 0; sl < nsteps; ++sl){
    const int s = p.s0 + sl;
    const float hbv = p.hb[(b0+w)*NSTEP + s];
    float gbv[8];
    #pragma unroll
    for (int nf = 0; nf < 8; ++nf) gbv[nf] = p.gb[((size_t)(b0+w)*NSTEP + s)*HID + nf*16 + n16];
    if (owner){
      #pragma unroll
      for (int nf = 0; nf < 8; ++nf) zsth[w*ZSTR + nf*16 + n16] = f2h(zc[nf]);
    }
    float ks[8];
    #pragma unroll
    for (int nf = 0; nf < 8; ++nf) ks[nf] = 0.f;
    const uint4* g4 = (const uint4*)(p.Gp + ((size_t)sl*BB + b0 + w)*16384);
    __syncthreads();

    #pragma unroll 1
    for (int st = 0; st < 4; ++st){
      // ---- layer1: zst(4x128) @ W1(128x256) ----
      f32x4 D[4];
      #pragma unroll
      for (int nf = 0; nf < 4; ++nf) D[nf] = (f32x4){0,0,0,0};
      #pragma unroll
      for (int kt = 0; kt < 4; ++kt){
        f16x8 a; uint4 av = ((const uint4*)zsth)[bl*17 + kt*4 + quad]; __builtin_memcpy(&a, &av, 16);
        #pragma unroll
        for (int nf = 0; nf < 4; ++nf){
          f16x8 bf; __builtin_memcpy(&bf, &w1r[kt*4+nf], 16);
          D[nf] = __builtin_amdgcn_mfma_f32_16x16x32_f16(a, bf, D[nf], 0, 0, 0);
        }
      }
      float v[4][4];
      #pragma unroll
      for (int nf = 0; nf < 4; ++nf)
        #pragma unroll
        for (int i = 0; i < 4; ++i) v[nf][i] = D[nf][i] + rb1[nf];
      float ms[4], rs[4];
      {
        float sm[4], sqv[4];
        #pragma unroll
        for (int i = 0; i < 4; ++i){
          sm[i]  = dpp16sum((v[0][i]+v[1][i]) + (v[2][i]+v[3][i]));
          sqv[i] = dpp16sum((v[0][i]*v[0][i]+v[1][i]*v[1][i]) + (v[2][i]*v[2][i]+v[3][i]*v[3][i]));
        }
        if (lane == 15){
          ((float4*)redl)[w*2]   = make_float4(sm[0], sqv[0], sm[1], sqv[1]);
          ((float4*)redl)[w*2+1] = make_float4(sm[2], sqv[2], sm[3], sqv[3]);
        }
        __syncthreads();                                   // b1
        const float4* r4 = (const float4*)redl;
        float4 r0=r4[0], r1=r4[1], r2=r4[2], r3=r4[3], r5=r4[4], r6=r4[5], r7=r4[6], r8=r4[7];
        ms[0]=((r0.x+r2.x)+(r5.x+r7.x))*(1.f/HID2); float q0=((r0.y+r2.y)+(r5.y+r7.y))*(1.f/HID2);
        ms[1]=((r0.z+r2.z)+(r5.z+r7.z))*(1.f/HID2); float q1=((r0.w+r2.w)+(r5.w+r7.w))*(1.f/HID2);
        ms[2]=((r1.x+r3.x)+(r6.x+r8.x))*(1.f/HID2); float q2=((r1.y+r3.y)+(r6.y+r8.y))*(1.f/HID2);
        ms[3]=((r1.z+r3.z)+(r6.z+r8.z))*(1.f/HID2); float q3=((r1.w+r3.w)+(r6.w+r8.w))*(1.f/HID2);
        rs[0]=rsqrtf(q0-ms[0]*ms[0]+1e-5f); rs[1]=rsqrtf(q1-ms[1]*ms[1]+1e-5f);
        rs[2]=rsqrtf(q2-ms[2]*ms[2]+1e-5f); rs[3]=rsqrtf(q3-ms[3]*ms[3]+1e-5f);
      }
      if (owner){
        #pragma unroll
        for (int nf = 0; nf < 4; ++nf)
          #pragma unroll
          for (int i = 0; i < 4; ++i)
            bufA[i*BSTR + w*64 + nf*16 + n16] = f2h(gelu_f((v[nf][i]-ms[i])*rs[i]*rg1[nf] + rbt1[nf]));
      }
      __syncthreads();                                     // b2
      // ---- layer2: a1(4x256) @ W2(256x256) ----
      #pragma unroll
      for (int nf = 0; nf < 4; ++nf) D[nf] = (f32x4){0,0,0,0};
      #pragma unroll
      for (int kt = 0; kt < 8; ++kt){
        f16x8 a; uint4 av = ((const uint4*)bufA)[bl*34 + kt*4 + quad]; __builtin_memcpy(&a, &av, 16);
        #pragma unroll
        for (int nf = 0; nf < 4; ++nf){
          f16x8 bf; __builtin_memcpy(&bf, &w2r[kt*4+nf], 16);
          D[nf] = __builtin_amdgcn_mfma_f32_16x16x32_f16(a, bf, D[nf], 0, 0, 0);
        }
      }
      #pragma unroll
      for (int nf = 0; nf < 4; ++nf)
        #pragma unroll
        for (int i = 0; i < 4; ++i) v[nf][i] = D[nf][i] + rb2[nf];
      {
        float sm[4], sqv[4];
        #pragma unroll
        for (int i = 0; i < 4; ++i){
          sm[i]  = dpp16sum((v[0][i]+v[1][i]) + (v[2][i]+v[3][i]));
          sqv[i] = dpp16sum((v[0][i]*v[0][i]+v[1][i]*v[1][i]) + (v[2][i]*v[2][i]+v[3][i]*v[3][i]));
        }
        if (lane == 15){
          ((float4*)redl)[w*2]   = make_float4(sm[0], sqv[0], sm[1], sqv[1]);
          ((float4*)redl)[w*2+1] = make_float4(sm[2], sqv[2], sm[3], sqv[3]);
        }
        __syncthreads();                                   // b3
        const float4* r4 = (const float4*)redl;
        float4 r0=r4[0], r1=r4[1], r2=r4[2], r3=r4[3], r5=r4[4], r6=r4[5], r7=r4[6], r8=r4[7];
        ms[0]=((r0.x+r2.x)+(r5.x+r7.x))*(1.f/HID2); float q0=((r0.y+r2.y)+(r5.y+r7.y))*(1.f/HID2);
        ms[1]=((r0.z+r2.z)+(r5.z+r7.z))*(1.f/HID2); float q1=((r0.w+r2.w)+(r5.w+r7.w))*(1.f/HID2);
        ms[2]=((r1.x+r3.x)+(r6.x+r8.x))*(1.f/HID2); float q2=((r1.y+r3.y)+(r6.y+r8.y))*(1.f/HID2);
        ms[3]=((r1.z+r3.z)+(r6.z+r8.z))*(1.f/HID2); float q3=((r1.w+r3.w)+(r6.w+r8.w))*(1.f/HID2);
        rs[0]=rsqrtf(q0-ms[0]*ms[0]+1e-5f); rs[1]=rsqrtf(q1-ms[1]*ms[1]+1e-5f);
        rs[2]=rsqrtf(q2-ms[2]*ms[2]+1e-5f); rs[3]=rsqrtf(q3-ms[3]*ms[3]+1e-5f);
      }
      if (owner){
        #pragma unroll
        for (int nf = 0; nf < 4; ++nf)
          #pragma unroll
          for (int i = 0; i < 4; ++i)
            bufB[i*BSTR + w*64 + nf*16 + n16] = f2h(gelu_f((v[nf][i]-ms[i])*rs[i]*rg2[nf] + rbt2[nf]));
      }
      __syncthreads();                                     // b4
      // ---- layer3: a2[batch w](1x256) @ G[batch w](256x128), wave-per-batch ----
      f32x4 E[8];
      #pragma unroll
      for (int nf = 0; nf < 8; ++nf) E[nf] = (f32x4){0,0,0,0};
      uint4 ga[8], gn[8];
      #pragma unroll
      for (int nf = 0; nf < 8; ++nf) ga[nf] = g4[nf*64 + lane];
      #pragma unroll
      for (int kt = 0; kt < 8; ++kt){
        if (kt < 7){
          #pragma unroll
          for (int nf = 0; nf < 8; ++nf) gn[nf] = g4[((kt+1)*8 + nf)*64 + lane];
        }
        f16x8 a; uint4 av = ((const uint4*)bufB)[w*34 + kt*4 + quad]; __builtin_memcpy(&a, &av, 16);
        #pragma unroll
        for (int nf = 0; nf < 8; ++nf){
          f16x8 gf; __builtin_memcpy(&gf, &ga[nf], 16);
          E[nf] = __builtin_amdgcn_mfma_f32_16x16x32_f16(a, gf, E[nf], 0, 0, 0);
        }
        if (kt < 7){
          #pragma unroll
          for (int nf = 0; nf < 8; ++nf) ga[nf] = gn[nf];
        }
      }
      const float c1 = (st == 0 || st == 3) ? 1.f : 2.f;
      const float cz = (st == 2) ? hbv : 0.5f*hbv;
      #pragma unroll
      for (int nf = 0; nf < 8; ++nf){
        float kv = E[nf][0] + gbv[nf];
        ks[nf] += c1*kv;
        if (st < 3 && owner) zsth[w*ZSTR + nf*16 + n16] = f2h(zc[nf] + cz*kv);
      }
      __syncthreads();                                     // b5
    }
    #pragma unroll
    for (int nf = 0; nf < 8; ++nf) zc[nf] += hbv*(1.f/6.f)*ks[nf];
  }

  if (p.do_epi){
    if (owner){
      #pragma unroll
      for (int nf = 0; nf < 8; ++nf) zf[w*HID + nf*16 + n16] = zc[nf];
    }
    __syncthreads();
    #pragma unroll 1
    for (int blq = 0; blq < BPB; ++blq){
      if (tid < HID){
        float v = p.bv[tid];
        #pragma unroll 8
        for (int h = 0; h < HID; ++h) v = fmaf(zf[blq*HID + h], p.Wv[h*HID + tid], v);
        e1[tid] = v;
      }
      __syncthreads();
      if (tid < HID){
        float f = p.bo[tid];
        #pragma unroll 8
        for (int h = 0; h < HID; ++h) f = fmaf(e1[h], p.Wo[h*HID + tid], f);
        e2[tid] = f;
      }
      __syncthreads();
      if (tid < HID){
        float hd = p.db1[tid];
        #pragma unroll 8
        for (int h = 0; h < HID; ++h) hd = fmaf(e2[h], p.dW1[h*HID + tid], hd);
        e1[tid] = gelu_f(hd);
      }
      __syncthreads();
      if (tid < 10){
        float t = p.db2[tid];
        #pragma unroll 8
        for (int h = 0; h < HID; ++h) t = fmaf(e1[h], p.dW2[h*10 + tid], t);
        p.out[(b0+blq)*10 + tid] = t;
      }
      if (tid == 0) p.out[BB*10 + b0 + blq] = 1.0f;   // softmax over singleton axis == 1
      __syncthreads();
    }
  } else {
    if (owner){
      #pragma unroll
      for (int nf = 0; nf < 8; ++nf) p.zstate[(size_t)(b0+w)*HID + nf*16 + n16] = zc[nf];
    }
  }
}

extern "C" void kernel_launch(void* const* d_in, const int* in_sizes, int n_in,
                              void* d_out, int out_size, void* d_ws, size_t ws_size,
                              hipStream_t stream){
  const float* path  = (const float*)d_in[0];
  const float* ts    = (const float*)d_in[1];
  const float* eW1   = (const float*)d_in[2];
  const float* eb1   = (const float*)d_in[3];
  const float* eg1   = (const float*)d_in[4];
  const float* ebt1  = (const float*)d_in[5];
  const float* eW2   = (const float*)d_in[6];
  const float* eb2   = (const float*)d_in[7];
  const float* eg2   = (const float*)d_in[8];
  const float* ebt2  = (const float*)d_in[9];
  const float* vW1   = (const float*)d_in[10];
  const float* vb1   = (const float*)d_in[11];
  const float* vg1   = (const float*)d_in[12];
  const float* vbt1  = (const float*)d_in[13];
  const float* vW2   = (const float*)d_in[14];
  const float* vb2   = (const float*)d_in[15];
  const float* vg2   = (const float*)d_in[16];
  const float* vbt2  = (const float*)d_in[17];
  const float* vW3   = (const float*)d_in[18];
  const float* vb3   = (const float*)d_in[19];
  const float* Wv    = (const float*)d_in[24];
  const float* bv    = (const float*)d_in[25];
  const float* Wo    = (const float*)d_in[26];
  const float* bo    = (const float*)d_in[27];
  const float* dW1   = (const float*)d_in[28];
  const float* db1   = (const float*)d_in[29];
  const float* dW2   = (const float*)d_in[30];
  const float* db2   = (const float*)d_in[31];

  char* wsb = (char*)d_ws;
  float* z_state = (float*)(wsb + 0);              // 64 KB
  u32*   dxh = (u32*)(wsb + 65536);                // 248 KB
  float* hb  = (float*)(wsb + 319488);             // 16 KB
  float* gb  = (float*)(wsb + 335872);             // 1.94 MB
  u32*   w3h = (u32*)(wsb + 2367488);              // 2 MB
  u32*   w1f = (u32*)(wsb + 4464640);              // 64 KB
  u32*   w2f = (u32*)(wsb + 4530176);              // 128 KB
  u32*   w1e = (u32*)(wsb + 4661248);              // 8 KB
  u32*   w2e = (u32*)(wsb + 4669440);              // 32 KB
  u32*   Gp  = (u32*)(wsb + 4702208);              // up to 248 MB

  hipLaunchKernelGGL(prep_misc, dim3(BB), dim3(128), 0, stream, path, ts, vb3, dxh, hb, gb);
  hipLaunchKernelGGL(pack_w3, dim3(2048), dim3(256), 0, stream, vW3, w3h);
  hipLaunchKernelGGL(pack_wf, dim3(232), dim3(256), 0, stream, vW1, vW2, eW1, eW2, w1f, w2f, w1e, w2e);

  const size_t per_step = (size_t)BB * 16384 * 4;  // 8 MB per step
  const size_t gbase = 4702208;
  size_t gav = (ws_size > gbase) ? (ws_size - gbase) : per_step;
  int chunk = (int)(gav / per_step);
  if (chunk < 1) chunk = 1;
  if (chunk > NSTEP) chunk = NSTEP;

  for (int s0 = 0; s0 < NSTEP; s0 += chunk){
    int cs = (NSTEP - s0 < chunk) ? (NSTEP - s0) : chunk;
    hipLaunchKernelGGL(gprep_h, dim3(64, cs), dim3(256), 0, stream, w3h, dxh, Gp, s0);
    ScanP P;
    P.path = path;
    P.w1e = w1e; P.w2e = w2e;
    P.eb1 = eb1; P.eg1 = eg1; P.ebt1 = ebt1;
    P.eb2 = eb2; P.eg2 = eg2; P.ebt2 = ebt2;
    P.w1f = w1f; P.w2f = w2f;
    P.b1 = vb1; P.g1 = vg1; P.bt1 = vbt1;
    P.b2 = vb2; P.g2 = vg2; P.bt2 = vbt2;
    P.Wv = Wv; P.bv = bv; P.Wo = Wo; P.bo = bo;
    P.dW1 = dW1; P.db1 = db1; P.dW2 = dW2; P.db2 = db2;
    P.hb = hb; P.gb = gb; P.Gp = Gp;
    P.zstate = z_state; P.out = (float*)d_out;
    P.s0 = s0; P.s1 = s0 + cs;
    P.do_enc = (s0 == 0) ? 1 : 0;
    P.do_epi = (s0 + cs == NSTEP) ? 1 : 0;
    hipLaunchKernelGGL(scan_kernel, dim3(NBLK), dim3(256), 0, stream, P);
  }
}

// Round 8
// 541.795 us; speedup vs baseline: 2.5100x; 2.5100x over previous
//
#include <hip/hip_runtime.h>
#include <hip/hip_bf16.h>

#define BB 128
#define SS 32
#define NSTEP 31
#define IND 32
#define HID 128
#define HID2 256

typedef unsigned short u16;
typedef unsigned int u32;
typedef _Float16 f16;
typedef f16 h2 __attribute__((ext_vector_type(2)));
typedef __fp16 fp16v2 __attribute__((ext_vector_type(2)));
typedef _Float16 f16x8 __attribute__((ext_vector_type(8)));
typedef float f32x4 __attribute__((ext_vector_type(4)));

__device__ __forceinline__ float dot2f(u32 a, u32 b, float c){
#if __has_builtin(__builtin_amdgcn_fdot2)
  h2 ha, hb; __builtin_memcpy(&ha, &a, 4); __builtin_memcpy(&hb, &b, 4);
  return __builtin_amdgcn_fdot2(ha, hb, c, false);
#else
  h2 ha, hb; __builtin_memcpy(&ha, &a, 4); __builtin_memcpy(&hb, &b, 4);
  return c + (float)ha[0]*(float)hb[0] + (float)ha[1]*(float)hb[1];
#endif
}
__device__ __forceinline__ u32 pkh2(float a, float b){
  fp16v2 r = __builtin_amdgcn_cvt_pkrtz(a, b);
  u32 u; __builtin_memcpy(&u, &r, 4); return u;
}
__device__ __forceinline__ u16 f2h(float f){ f16 h = (f16)f; u16 u; __builtin_memcpy(&u, &h, 2); return u; }
__device__ __forceinline__ float gelu_f(float x){ return 0.5f * x * (1.0f + erff(x * 0.70710678118654752440f)); }

// DPP wave64 sum -> valid in lane 63
__device__ __forceinline__ float wred(float v){
  int iv; float tf;
  #define DPPADD(CTRL, RMASK) \
    __builtin_memcpy(&iv, &v, 4); \
    iv = __builtin_amdgcn_update_dpp(0, iv, CTRL, RMASK, 0xf, true); \
    __builtin_memcpy(&tf, &iv, 4); \
    v += tf;
  DPPADD(0x111, 0xf)
  DPPADD(0x112, 0xf)
  DPPADD(0x114, 0xf)
  DPPADD(0x118, 0xf)
  DPPADD(0x142, 0xa)
  DPPADD(0x143, 0xc)
  #undef DPPADD
  return v;
}

// block-wide sum of (x,y) over 256 threads — enc/epi only
__device__ __forceinline__ void bsum2(float x, float y, float* red, int tid, float& ox, float& oy){
  #pragma unroll
  for (int off = 32; off >= 1; off >>= 1){ x += __shfl_xor(x, off); y += __shfl_xor(y, off); }
  __syncthreads();
  if ((tid & 63) == 0){ red[(tid >> 6)*2] = x; red[(tid >> 6)*2 + 1] = y; }
  __syncthreads();
  ox = red[0] + red[2] + red[4] + red[6];
  oy = red[1] + red[3] + red[5] + red[7];
}

// ---------------- prep: dxh (packed half2 dX), hb, gb ----------------
__global__ __launch_bounds__(128) void prep_misc(const float* __restrict__ path,
                                                 const float* __restrict__ ts,
                                                 const float* __restrict__ b3,
                                                 u32* __restrict__ dxh,
                                                 float* __restrict__ hb,
                                                 float* __restrict__ gb){
  const int b = blockIdx.x, tid = threadIdx.x;
  __shared__ float sdxp[NSTEP * IND];
  for (int t = tid; t < NSTEP * IND; t += 128){
    int s = t >> 5, i = t & 31;
    float dt = ts[b*SS + s + 1] - ts[b*SS + s];
    sdxp[t] = (path[(b*SS + s + 1)*IND + i] - path[(b*SS + s)*IND + i]) / dt;
  }
  if (tid < NSTEP) hb[b*NSTEP + tid] = ts[b*SS + tid + 1] - ts[b*SS + tid];
  __syncthreads();
  for (int t = tid; t < NSTEP * 16; t += 128){
    int s = t >> 4, i2 = t & 15;
    dxh[((size_t)b*NSTEP + s)*16 + i2] = pkh2(sdxp[s*IND + 2*i2], sdxp[s*IND + 2*i2 + 1]);
  }
  if (tid < HID){
    float w[IND];
    #pragma unroll
    for (int i = 0; i < IND; ++i) w[i] = b3[tid*IND + i];
    for (int s = 0; s < NSTEP; ++s){
      float a = 0.f;
      #pragma unroll
      for (int i = 0; i < IND; ++i) a = fmaf(w[i], sdxp[s*IND + i], a);
      gb[(b*NSTEP + s)*HID + tid] = a;
    }
  }
}

// ---------------- pack vf_W3 (fp32) -> half2 pairs over i ----------------
__global__ __launch_bounds__(256) void pack_w3(const float* __restrict__ W3, u32* __restrict__ w3h){
  int i = blockIdx.x*256 + threadIdx.x;
  if (i < (HID2*HID*IND)/2) w3h[i] = pkh2(W3[2*i], W3[2*i + 1]);
}

// ---------------- pack W1/W2 into per-lane MFMA B-fragment order ----------------
__global__ __launch_bounds__(256) void pack_wf(const float* __restrict__ W1,
                                               const float* __restrict__ W2,
                                               u32* __restrict__ w1f,
                                               u32* __restrict__ w2f){
  int i = blockIdx.x*256 + threadIdx.x;
  if (i < 16384){
    int lane_blk = i >> 6, rem = i & 63;
    int i16 = rem >> 2, q = rem & 3;
    int w = lane_blk >> 6, lane = lane_blk & 63;
    int kt = i16 >> 2, nt = i16 & 3;
    int k = kt*32 + (lane >> 4)*8 + 2*q;
    int col = w*64 + nt*16 + (lane & 15);
    w1f[i] = pkh2(W1[(size_t)k*HID2 + col], W1[(size_t)(k+1)*HID2 + col]);
  } else if (i < 16384 + 32768){
    int j = i - 16384;
    int lane_blk = j >> 7, rem = j & 127;
    int i32i = rem >> 2, q = rem & 3;
    int w = lane_blk >> 6, lane = lane_blk & 63;
    int kt = i32i >> 2, nt = i32i & 3;
    int k = kt*32 + (lane >> 4)*8 + 2*q;
    int col = w*64 + nt*16 + (lane & 15);
    w2f[j] = pkh2(W2[(size_t)k*HID2 + col], W2[(size_t)(k+1)*HID2 + col]);
  }
}

// ---------------- fused scan + G-prep ----------------
struct FusedP {
  // scan
  const float *path;
  const float *eW1,*eb1,*eg1,*ebt1,*eW2,*eb2,*eg2,*ebt2;
  const u32 *w1f, *w2f;
  const float *b1,*g1,*bt1,*b2,*g2,*bt2;
  const float *Wv,*bv,*Wo,*bo,*dW1,*db1,*dW2,*db2;
  const float *hb,*gb;
  const u32 *Gp;          // scan-consumed buffer
  float *zstate, *out;
  int s0, s1, do_enc, do_epi, scan_on;
  // prep
  const u32 *w3h, *dxh;
  u32 *Gpw;               // prep-written buffer
  int ps0, pcs;
};

__global__ __launch_bounds__(256, 1) void fused_kernel(FusedP p){
  const int tid = threadIdx.x;
  // scan shared
  __shared__ __align__(16) u16 zst_h[HID];
  __shared__ __align__(16) u16 a1p_h[HID2];
  __shared__ __align__(16) u16 a2p_h[HID2];
  __shared__ __align__(16) float red[8];
  __shared__ __align__(16) float zf[HID];
  __shared__ __align__(16) float sc1[HID2];
  // prep shared
  __shared__ u32 sdx[BB * 16];

  if (p.scan_on && blockIdx.x < BB){
    // ================= SCAN (verified R6 body) =================
    const int b = blockIdx.x;
    const int lane = tid & 63, w = tid >> 6;
    const int quad = lane >> 4, n16 = lane & 15;
    const bool owner = (quad == 0);

    uint4 w1r[16], w2r[32];
    {
      const uint4* s1p = (const uint4*)p.w1f + ((size_t)(w*64 + lane))*16;
      #pragma unroll
      for (int i = 0; i < 16; ++i) w1r[i] = s1p[i];
      const uint4* s2p = (const uint4*)p.w2f + ((size_t)(w*64 + lane))*32;
      #pragma unroll
      for (int i = 0; i < 32; ++i) w2r[i] = s2p[i];
    }
    float rb1[4], rg1[4], rbt1[4], rb2[4], rg2[4], rbt2[4];
    #pragma unroll
    for (int nt = 0; nt < 4; ++nt){
      int col = w*64 + nt*16 + n16;
      rb1[nt] = p.b1[col]; rg1[nt] = p.g1[col]; rbt1[nt] = p.bt1[col];
      rb2[nt] = p.b2[col]; rg2[nt] = p.g2[col]; rbt2[nt] = p.bt2[col];
    }
    const int h0 = w*32 + n16, h1 = h0 + 16;

    float mu, sq;
    if (p.do_enc){
      if (tid < IND) sc1[tid] = p.path[(b*SS + 0)*IND + tid];
      __syncthreads();
      float acc = 0.f;
      if (tid < HID){
        acc = p.eb1[tid];
        #pragma unroll 8
        for (int i = 0; i < IND; ++i) acc = fmaf(sc1[i], p.eW1[i*HID + tid], acc);
      }
      float cx = (tid < HID) ? acc : 0.f;
      bsum2(cx, cx*cx, red, tid, mu, sq);
      mu *= (1.f/HID); float var = sq*(1.f/HID) - mu*mu; float rstd = rsqrtf(var + 1e-5f);
      if (tid < HID) zf[tid] = gelu_f((acc - mu)*rstd*p.eg1[tid] + p.ebt1[tid]);
      __syncthreads();
      float acc2 = 0.f;
      if (tid < HID){
        acc2 = p.eb2[tid];
        #pragma unroll 8
        for (int h = 0; h < HID; ++h) acc2 = fmaf(zf[h], p.eW2[h*HID + tid], acc2);
      }
      cx = (tid < HID) ? acc2 : 0.f;
      bsum2(cx, cx*cx, red, tid, mu, sq);
      mu *= (1.f/HID); float var2 = sq*(1.f/HID) - mu*mu; float rstd2 = rsqrtf(var2 + 1e-5f);
      __syncthreads();
      if (tid < HID) zf[tid] = (acc2 - mu)*rstd2*p.eg2[tid] + p.ebt2[tid];
      __syncthreads();
    }
    float zc0 = 0.f, zc1 = 0.f;
    if (owner){
      if (p.do_enc){ zc0 = zf[h0]; zc1 = zf[h1]; }
      else { zc0 = p.zstate[b*HID + h0]; zc1 = p.zstate[b*HID + h1]; }
    }

    for (int s = p.s0; s < p.s1; ++s){
      const float hbv = p.hb[b*NSTEP + s];
      uint4 gr[16];
      {
        const uint4* g4 = (const uint4*)(p.Gp + ((size_t)(s - p.s0)*BB + b)*16384 + (size_t)w*4096);
        #pragma unroll
        for (int m = 0; m < 16; ++m) gr[m] = g4[m*64 + lane];
      }
      float gb0 = 0.f, gb1 = 0.f;
      if (owner){
        gb0 = p.gb[(b*NSTEP + s)*HID + h0];
        gb1 = p.gb[(b*NSTEP + s)*HID + h1];
        zst_h[h0] = f2h(zc0); zst_h[h1] = f2h(zc1);
      }
      float ks0 = 0.f, ks1 = 0.f;
      __syncthreads();

      #pragma unroll 1
      for (int st = 0; st < 4; ++st){
        // layer1: zst(1x128) @ W1(128x256), 16 MFMA
        f32x4 D0 = {0,0,0,0}, D1 = {0,0,0,0}, D2 = {0,0,0,0}, D3 = {0,0,0,0};
        {
          const uint4* za = (const uint4*)zst_h;
          #pragma unroll
          for (int kt = 0; kt < 4; ++kt){
            f16x8 a; uint4 av = za[kt*4 + quad]; __builtin_memcpy(&a, &av, 16);
            f16x8 bf;
            __builtin_memcpy(&bf, &w1r[kt*4+0], 16); D0 = __builtin_amdgcn_mfma_f32_16x16x32_f16(a, bf, D0, 0, 0, 0);
            __builtin_memcpy(&bf, &w1r[kt*4+1], 16); D1 = __builtin_amdgcn_mfma_f32_16x16x32_f16(a, bf, D1, 0, 0, 0);
            __builtin_memcpy(&bf, &w1r[kt*4+2], 16); D2 = __builtin_amdgcn_mfma_f32_16x16x32_f16(a, bf, D2, 0, 0, 0);
            __builtin_memcpy(&bf, &w1r[kt*4+3], 16); D3 = __builtin_amdgcn_mfma_f32_16x16x32_f16(a, bf, D3, 0, 0, 0);
          }
        }
        float v0 = D0[0] + rb1[0], v1 = D1[0] + rb1[1], v2 = D2[0] + rb1[2], v3 = D3[0] + rb1[3];
        float ssum = wred((v0 + v1) + (v2 + v3));
        float ssq  = wred((v0*v0 + v1*v1) + (v2*v2 + v3*v3));
        if (lane == 63){ red[w*2] = ssum; red[w*2+1] = ssq; }
        __syncthreads();                                    // b1
        {
          const float4* r4 = (const float4*)red;
          float4 ra = r4[0], rb = r4[1];
          float m1 = (ra.x + ra.z + rb.x + rb.z)*(1.f/1024.f);
          float q1 = (ra.y + ra.w + rb.y + rb.w)*(1.f/1024.f);
          float rs1 = rsqrtf(q1 - m1*m1 + 1e-5f);
          if (owner){
            a1p_h[w*64 +  0 + n16] = f2h(gelu_f((v0 - m1)*rs1*rg1[0] + rbt1[0]));
            a1p_h[w*64 + 16 + n16] = f2h(gelu_f((v1 - m1)*rs1*rg1[1] + rbt1[1]));
            a1p_h[w*64 + 32 + n16] = f2h(gelu_f((v2 - m1)*rs1*rg1[2] + rbt1[2]));
            a1p_h[w*64 + 48 + n16] = f2h(gelu_f((v3 - m1)*rs1*rg1[3] + rbt1[3]));
          }
        }
        __syncthreads();                                    // b2
        // layer2: a1(1x256) @ W2(256x256), 32 MFMA
        D0 = {0,0,0,0}; D1 = {0,0,0,0}; D2 = {0,0,0,0}; D3 = {0,0,0,0};
        {
          const uint4* aa = (const uint4*)a1p_h;
          #pragma unroll
          for (int kt = 0; kt < 8; ++kt){
            f16x8 a; uint4 av = aa[kt*4 + quad]; __builtin_memcpy(&a, &av, 16);
            f16x8 bf;
            __builtin_memcpy(&bf, &w2r[kt*4+0], 16); D0 = __builtin_amdgcn_mfma_f32_16x16x32_f16(a, bf, D0, 0, 0, 0);
            __builtin_memcpy(&bf, &w2r[kt*4+1], 16); D1 = __builtin_amdgcn_mfma_f32_16x16x32_f16(a, bf, D1, 0, 0, 0);
            __builtin_memcpy(&bf, &w2r[kt*4+2], 16); D2 = __builtin_amdgcn_mfma_f32_16x16x32_f16(a, bf, D2, 0, 0, 0);
            __builtin_memcpy(&bf, &w2r[kt*4+3], 16); D3 = __builtin_amdgcn_mfma_f32_16x16x32_f16(a, bf, D3, 0, 0, 0);
          }
        }
        v0 = D0[0] + rb2[0]; v1 = D1[0] + rb2[1]; v2 = D2[0] + rb2[2]; v3 = D3[0] + rb2[3];
        ssum = wred((v0 + v1) + (v2 + v3));
        ssq  = wred((v0*v0 + v1*v1) + (v2*v2 + v3*v3));
        if (lane == 63){ red[w*2] = ssum; red[w*2+1] = ssq; }
        __syncthreads();                                    // b3
        {
          const float4* r4 = (const float4*)red;
          float4 ra = r4[0], rb = r4[1];
          float m2 = (ra.x + ra.z + rb.x + rb.z)*(1.f/1024.f);
          float q2 = (ra.y + ra.w + rb.y + rb.w)*(1.f/1024.f);
          float rs2 = rsqrtf(q2 - m2*m2 + 1e-5f);
          if (owner){
            a2p_h[w*64 +  0 + n16] = f2h(gelu_f((v0 - m2)*rs2*rg2[0] + rbt2[0]));
            a2p_h[w*64 + 16 + n16] = f2h(gelu_f((v1 - m2)*rs2*rg2[1] + rbt2[1]));
            a2p_h[w*64 + 32 + n16] = f2h(gelu_f((v2 - m2)*rs2*rg2[2] + rbt2[2]));
            a2p_h[w*64 + 48 + n16] = f2h(gelu_f((v3 - m2)*rs2*rg2[3] + rbt2[3]));
          }
        }
        __syncthreads();                                    // b4
        // layer3: a2(1x256) @ G(256x32 cols of this wave), 16 MFMA
        f32x4 E0 = {0,0,0,0}, E1 = {0,0,0,0};
        {
          const uint4* aa = (const uint4*)a2p_h;
          #pragma unroll
          for (int kt = 0; kt < 8; ++kt){
            f16x8 a; uint4 av = aa[kt*4 + quad]; __builtin_memcpy(&a, &av, 16);
            f16x8 g0f, g1f;
            __builtin_memcpy(&g0f, &gr[kt*2+0], 16);
            __builtin_memcpy(&g1f, &gr[kt*2+1], 16);
            E0 = __builtin_amdgcn_mfma_f32_16x16x32_f16(a, g0f, E0, 0, 0, 0);
            E1 = __builtin_amdgcn_mfma_f32_16x16x32_f16(a, g1f, E1, 0, 0, 0);
          }
        }
        if (owner){
          float kv0 = E0[0] + gb0, kv1 = E1[0] + gb1;
          float cst = (st == 0 || st == 3) ? 1.f : 2.f;
          ks0 += cst*kv0; ks1 += cst*kv1;
          if (st < 3){
            float c = (st == 2) ? hbv : 0.5f*hbv;
            zst_h[h0] = f2h(zc0 + c*kv0);
            zst_h[h1] = f2h(zc1 + c*kv1);
          }
        }
        __syncthreads();                                    // b5
      }
      if (owner){ zc0 += hbv*(1.f/6.f)*ks0; zc1 += hbv*(1.f/6.f)*ks1; }
    }

    if (p.do_epi){
      if (owner){ zf[h0] = zc0; zf[h1] = zc1; }
      __syncthreads();
      if (tid < HID){
        float v = p.bv[tid];
        #pragma unroll 8
        for (int h = 0; h < HID; ++h) v = fmaf(zf[h], p.Wv[h*HID + tid], v);
        sc1[tid] = v;
      }
      __syncthreads();
      if (tid < HID){
        float f = p.bo[tid];
        #pragma unroll 8
        for (int h = 0; h < HID; ++h) f = fmaf(sc1[h], p.Wo[h*HID + tid], f);
        sc1[HID + tid] = f;
      }
      __syncthreads();
      if (tid < HID){
        float hd = p.db1[tid];
        #pragma unroll 8
        for (int h = 0; h < HID; ++h) hd = fmaf(sc1[HID + h], p.dW1[h*HID + tid], hd);
        zf[tid] = gelu_f(hd);
      }
      __syncthreads();
      if (tid < 10){
        float t = p.db2[tid];
        #pragma unroll 8
        for (int h = 0; h < HID; ++h) t = fmaf(zf[h], p.dW2[h*10 + tid], t);
        p.out[b*10 + tid] = t;
      }
      if (tid == 0) p.out[BB*10 + b] = 1.0f;   // softmax over singleton axis == 1
    } else {
      if (owner){ p.zstate[b*HID + h0] = zc0; p.zstate[b*HID + h1] = zc1; }
    }
    return;
  }

  // ================= G-PREP (verified R6 body) =================
  {
    const int pb = blockIdx.x - (p.scan_on ? BB : 0);
    const int sl = pb >> 6, xblk = pb & 63;
    if (sl >= p.pcs) return;
    const int s = p.ps0 + sl;
    const int lin = xblk*256 + tid;              // (kp, h)
    const int kp = lin >> 7, h = lin & 127;
    const uint4* wa = (const uint4*)(p.w3h + ((size_t)(2*kp)*HID + h)*16);
    const uint4* wb = (const uint4*)(p.w3h + ((size_t)(2*kp+1)*HID + h)*16);
    uint4 A0 = wa[0], A1 = wa[1], A2 = wa[2], A3 = wa[3];
    uint4 B0 = wb[0], B1 = wb[1], B2 = wb[2], B3 = wb[3];
    for (int t = tid; t < BB * 16; t += 256){
      int bb = t >> 4, i2 = t & 15;
      sdx[t] = p.dxh[((size_t)bb*NSTEP + s)*16 + i2];
    }
    __syncthreads();
    // fragment-layout output offset
    const int kt = kp >> 4, q = kp & 3, quad2 = (kp >> 2) & 3;
    const int wq = h >> 5, tq = (h >> 4) & 1, nn = h & 15;
    const size_t off = (size_t)wq*4096 + (size_t)(kt*2 + tq)*256 + (size_t)(quad2*16 + nn)*4 + q;
    const size_t base_sl = (size_t)sl * BB * 16384;
    u32* __restrict__ Gout = p.Gpw;
    for (int bb = 0; bb < BB; ++bb){
      const uint4* dp = (const uint4*)&sdx[bb*16];
      uint4 D0 = dp[0], D1 = dp[1], D2 = dp[2], D3 = dp[3];
      float g0 = 0.f, g1 = 0.f, g2 = 0.f, g3 = 0.f;
      g0 = dot2f(D0.x, A0.x, g0); g0 = dot2f(D0.y, A0.y, g0);
      g0 = dot2f(D0.z, A0.z, g0); g0 = dot2f(D0.w, A0.w, g0);
      g2 = dot2f(D1.x, A1.x, g2); g2 = dot2f(D1.y, A1.y, g2);
      g2 = dot2f(D1.z, A1.z, g2); g2 = dot2f(D1.w, A1.w, g2);
      g0 = dot2f(D2.x, A2.x, g0); g0 = dot2f(D2.y, A2.y, g0);
      g0 = dot2f(D2.z, A2.z, g0); g0 = dot2f(D2.w, A2.w, g0);
      g2 = dot2f(D3.x, A3.x, g2); g2 = dot2f(D3.y, A3.y, g2);
      g2 = dot2f(D3.z, A3.z, g2); g2 = dot2f(D3.w, A3.w, g2);
      g1 = dot2f(D0.x, B0.x, g1); g1 = dot2f(D0.y, B0.y, g1);
      g1 = dot2f(D0.z, B0.z, g1); g1 = dot2f(D0.w, B0.w, g1);
      g3 = dot2f(D1.x, B1.x, g3); g3 = dot2f(D1.y, B1.y, g3);
      g3 = dot2f(D1.z, B1.z, g3); g3 = dot2f(D1.w, B1.w, g3);
      g1 = dot2f(D2.x, B2.x, g1); g1 = dot2f(D2.y, B2.y, g1);
      g1 = dot2f(D2.z, B2.z, g1); g1 = dot2f(D2.w, B2.w, g1);
      g3 = dot2f(D3.x, B3.x, g3); g3 = dot2f(D3.y, B3.y, g3);
      g3 = dot2f(D3.z, B3.z, g3); g3 = dot2f(D3.w, B3.w, g3);
      Gout[base_sl + (size_t)bb*16384 + off] = pkh2(g0 + g2, g1 + g3);
    }
  }
}

extern "C" void kernel_launch(void* const* d_in, const int* in_sizes, int n_in,
                              void* d_out, int out_size, void* d_ws, size_t ws_size,
                              hipStream_t stream){
  const float* path  = (const float*)d_in[0];
  const float* ts    = (const float*)d_in[1];
  const float* eW1   = (const float*)d_in[2];
  const float* eb1   = (const float*)d_in[3];
  const float* eg1   = (const float*)d_in[4];
  const float* ebt1  = (const float*)d_in[5];
  const float* eW2   = (const float*)d_in[6];
  const float* eb2   = (const float*)d_in[7];
  const float* eg2   = (const float*)d_in[8];
  const float* ebt2  = (const float*)d_in[9];
  const float* vW1   = (const float*)d_in[10];
  const float* vb1   = (const float*)d_in[11];
  const float* vg1   = (const float*)d_in[12];
  const float* vbt1  = (const float*)d_in[13];
  const float* vW2   = (const float*)d_in[14];
  const float* vb2   = (const float*)d_in[15];
  const float* vg2   = (const float*)d_in[16];
  const float* vbt2  = (const float*)d_in[17];
  const float* vW3   = (const float*)d_in[18];
  const float* vb3   = (const float*)d_in[19];
  const float* Wv    = (const float*)d_in[24];
  const float* bv    = (const float*)d_in[25];
  const float* Wo    = (const float*)d_in[26];
  const float* bo    = (const float*)d_in[27];
  const float* dW1   = (const float*)d_in[28];
  const float* db1   = (const float*)d_in[29];
  const float* dW2   = (const float*)d_in[30];
  const float* db2   = (const float*)d_in[31];

  char* wsb = (char*)d_ws;
  float* z_state = (float*)(wsb + 0);              // 64 KB
  u32*   dxh = (u32*)(wsb + 65536);                // 248 KB
  float* hb  = (float*)(wsb + 319488);             // 16 KB
  float* gb  = (float*)(wsb + 335872);             // 1.94 MB
  u32*   w3h = (u32*)(wsb + 2367488);              // 2 MB
  u32*   w1f = (u32*)(wsb + 4464640);              // 64 KB
  u32*   w2f = (u32*)(wsb + 4530176);              // 128 KB
  const size_t gbase = 4661248;

  hipLaunchKernelGGL(prep_misc, dim3(BB), dim3(128), 0, stream, path, ts, vb3, dxh, hb, gb);
  hipLaunchKernelGGL(pack_w3, dim3(2048), dim3(256), 0, stream, vW3, w3h);
  hipLaunchKernelGGL(pack_wf, dim3(192), dim3(256), 0, stream, vW1, vW2, w1f, w2f);

  const size_t per_step = (size_t)BB * 16384 * 4;  // 8 MB per step
  size_t avail = (ws_size > gbase) ? (ws_size - gbase) : 0;
  int pipelined, c;
  int capp = (int)((avail/2) / per_step);
  if (capp >= 2){
    pipelined = 1;
    c = capp < 8 ? capp : 8;
    if (c > NSTEP) c = NSTEP;
  } else {
    pipelined = 0;
    c = (int)(avail / per_step);
    if (c < 1) c = 1;
    if (c > NSTEP) c = NSTEP;
  }
  const int nch = (NSTEP + c - 1) / c;
  u32* GpA = (u32*)(wsb + gbase);
  u32* GpB = (u32*)(wsb + gbase + (size_t)c*per_step);

  FusedP base;
  base.path = path;
  base.eW1 = eW1; base.eb1 = eb1; base.eg1 = eg1; base.ebt1 = ebt1;
  base.eW2 = eW2; base.eb2 = eb2; base.eg2 = eg2; base.ebt2 = ebt2;
  base.w1f = w1f; base.w2f = w2f;
  base.b1 = vb1; base.g1 = vg1; base.bt1 = vbt1;
  base.b2 = vb2; base.g2 = vg2; base.bt2 = vbt2;
  base.Wv = Wv; base.bv = bv; base.Wo = Wo; base.bo = bo;
  base.dW1 = dW1; base.db1 = db1; base.dW2 = dW2; base.db2 = db2;
  base.hb = hb; base.gb = gb;
  base.zstate = z_state; base.out = (float*)d_out;
  base.w3h = w3h; base.dxh = dxh;
  base.Gp = GpA; base.Gpw = GpA;
  base.s0 = 0; base.s1 = 0; base.do_enc = 0; base.do_epi = 0; base.scan_on = 0;
  base.ps0 = 0; base.pcs = 0;

  if (pipelined){
    for (int i = 0; i <= nch; ++i){
      FusedP P = base;
      int scan_i = i - 1, prep_i = i;
      P.scan_on = (scan_i >= 0) ? 1 : 0;
      if (P.scan_on){
        P.s0 = scan_i*c;
        P.s1 = (P.s0 + c < NSTEP) ? (P.s0 + c) : NSTEP;
        P.Gp = (scan_i & 1) ? GpB : GpA;
        P.do_enc = (scan_i == 0) ? 1 : 0;
        P.do_epi = (P.s1 == NSTEP) ? 1 : 0;
      }
      if (prep_i < nch){
        P.ps0 = prep_i*c;
        P.pcs = (NSTEP - P.ps0 < c) ? (NSTEP - P.ps0) : c;
        P.Gpw = (prep_i & 1) ? GpB : GpA;
      } else {
        P.pcs = 0;
      }
      int grid = (P.scan_on ? BB : 0) + 64*P.pcs;
      if (grid == 0) continue;
      hipLaunchKernelGGL(fused_kernel, dim3(grid), dim3(256), 0, stream, P);
    }
  } else {
    for (int i = 0; i < nch; ++i){
      int s0 = i*c;
      int cs = (NSTEP - s0 < c) ? (NSTEP - s0) : c;
      FusedP P1 = base;                 // prep only
      P1.scan_on = 0; P1.ps0 = s0; P1.pcs = cs; P1.Gpw = GpA;
      hipLaunchKernelGGL(fused_kernel, dim3(64*cs), dim3(256), 0, stream, P1);
      FusedP P2 = base;                 // scan only
      P2.scan_on = 1; P2.pcs = 0;
      P2.s0 = s0; P2.s1 = s0 + cs; P2.Gp = GpA;
      P2.do_enc = (s0 == 0) ? 1 : 0;
      P2.do_epi = (s0 + cs == NSTEP) ? 1 : 0;
      hipLaunchKernelGGL(fused_kernel, dim3(BB), dim3(256), 0, stream, P2);
    }
  }
}

// Round 10
// 521.521 us; speedup vs baseline: 2.6075x; 1.0389x over previous
//
#include <hip/hip_runtime.h>
#include <hip/hip_bf16.h>

#define BB 128
#define SS 32
#define NSTEP 31
#define IND 32
#define HID 128
#define HID2 256

typedef unsigned short u16;
typedef unsigned int u32;
typedef _Float16 f16;
typedef f16 h2 __attribute__((ext_vector_type(2)));
typedef __fp16 fp16v2 __attribute__((ext_vector_type(2)));
typedef _Float16 f16x8 __attribute__((ext_vector_type(8)));
typedef float f32x4 __attribute__((ext_vector_type(4)));

__device__ __forceinline__ float dot2f(u32 a, u32 b, float c){
#if __has_builtin(__builtin_amdgcn_fdot2)
  h2 ha, hb; __builtin_memcpy(&ha, &a, 4); __builtin_memcpy(&hb, &b, 4);
  return __builtin_amdgcn_fdot2(ha, hb, c, false);
#else
  h2 ha, hb; __builtin_memcpy(&ha, &a, 4); __builtin_memcpy(&hb, &b, 4);
  return c + (float)ha[0]*(float)hb[0] + (float)ha[1]*(float)hb[1];
#endif
}
__device__ __forceinline__ u32 pkh2(float a, float b){
  fp16v2 r = __builtin_amdgcn_cvt_pkrtz(a, b);
  u32 u; __builtin_memcpy(&u, &r, 4); return u;
}
__device__ __forceinline__ u16 f2h(float f){ f16 h = (f16)f; u16 u; __builtin_memcpy(&u, &h, 2); return u; }
__device__ __forceinline__ float gelu_f(float x){ return 0.5f * x * (1.0f + erff(x * 0.70710678118654752440f)); }
__device__ __forceinline__ void setprio_hi(){
#if __has_builtin(__builtin_amdgcn_s_setprio)
  __builtin_amdgcn_s_setprio(3);
#endif
}
__device__ __forceinline__ void setprio_lo(){
#if __has_builtin(__builtin_amdgcn_s_setprio)
  __builtin_amdgcn_s_setprio(0);
#endif
}

// DPP wave64 sum -> valid in lane 63
__device__ __forceinline__ float wred(float v){
  int iv; float tf;
  #define DPPADD(CTRL, RMASK) \
    __builtin_memcpy(&iv, &v, 4); \
    iv = __builtin_amdgcn_update_dpp(0, iv, CTRL, RMASK, 0xf, true); \
    __builtin_memcpy(&tf, &iv, 4); \
    v += tf;
  DPPADD(0x111, 0xf)
  DPPADD(0x112, 0xf)
  DPPADD(0x114, 0xf)
  DPPADD(0x118, 0xf)
  DPPADD(0x142, 0xa)
  DPPADD(0x143, 0xc)
  #undef DPPADD
  return v;
}

// block-wide sum of (x,y) over 256 threads — enc/epi only
__device__ __forceinline__ void bsum2(float x, float y, float* red, int tid, float& ox, float& oy){
  #pragma unroll
  for (int off = 32; off >= 1; off >>= 1){ x += __shfl_xor(x, off); y += __shfl_xor(y, off); }
  __syncthreads();
  if ((tid & 63) == 0){ red[(tid >> 6)*2] = x; red[(tid >> 6)*2 + 1] = y; }
  __syncthreads();
  ox = red[0] + red[2] + red[4] + red[6];
  oy = red[1] + red[3] + red[5] + red[7];
}

// ---------------- merged setup: prep_misc / pack_w3 / pack_wf ----------------
__global__ __launch_bounds__(256) void setup_kernel(const float* __restrict__ path,
                                                    const float* __restrict__ ts,
                                                    const float* __restrict__ b3,
                                                    const float* __restrict__ W3,
                                                    const float* __restrict__ W1,
                                                    const float* __restrict__ W2,
                                                    u32* __restrict__ dxh,
                                                    float* __restrict__ hb,
                                                    float* __restrict__ gb,
                                                    u32* __restrict__ w3h,
                                                    u32* __restrict__ w1f,
                                                    u32* __restrict__ w2f){
  const int blk = blockIdx.x, tid = threadIdx.x;
  if (blk < BB){
    // ---- prep_misc for batch b = blk ----
    const int b = blk;
    __shared__ float sdxp[NSTEP * IND];
    for (int t = tid; t < NSTEP * IND; t += 256){
      int s = t >> 5, i = t & 31;
      float dt = ts[b*SS + s + 1] - ts[b*SS + s];
      sdxp[t] = (path[(b*SS + s + 1)*IND + i] - path[(b*SS + s)*IND + i]) / dt;
    }
    if (tid < NSTEP) hb[b*NSTEP + tid] = ts[b*SS + tid + 1] - ts[b*SS + tid];
    __syncthreads();
    for (int t = tid; t < NSTEP * 16; t += 256){
      int s = t >> 4, i2 = t & 15;
      dxh[((size_t)b*NSTEP + s)*16 + i2] = pkh2(sdxp[s*IND + 2*i2], sdxp[s*IND + 2*i2 + 1]);
    }
    if (tid < HID){
      float w[IND];
      #pragma unroll
      for (int i = 0; i < IND; ++i) w[i] = b3[tid*IND + i];
      for (int s = 0; s < NSTEP; ++s){
        float a = 0.f;
        #pragma unroll
        for (int i = 0; i < IND; ++i) a = fmaf(w[i], sdxp[s*IND + i], a);
        gb[(b*NSTEP + s)*HID + tid] = a;
      }
    }
  } else if (blk < BB + 2048){
    int i = (blk - BB)*256 + tid;
    if (i < (HID2*HID*IND)/2) w3h[i] = pkh2(W3[2*i], W3[2*i + 1]);
  } else {
    int i = (blk - BB - 2048)*256 + tid;
    if (i < 16384){
      int lane_blk = i >> 6, rem = i & 63;
      int i16 = rem >> 2, q = rem & 3;
      int w = lane_blk >> 6, lane = lane_blk & 63;
      int kt = i16 >> 2, nt = i16 & 3;
      int k = kt*32 + (lane >> 4)*8 + 2*q;
      int col = w*64 + nt*16 + (lane & 15);
      w1f[i] = pkh2(W1[(size_t)k*HID2 + col], W1[(size_t)(k+1)*HID2 + col]);
    } else if (i < 16384 + 32768){
      int j = i - 16384;
      int lane_blk = j >> 7, rem = j & 127;
      int i32i = rem >> 2, q = rem & 3;
      int w = lane_blk >> 6, lane = lane_blk & 63;
      int kt = i32i >> 2, nt = i32i & 3;
      int k = kt*32 + (lane >> 4)*8 + 2*q;
      int col = w*64 + nt*16 + (lane & 15);
      w2f[j] = pkh2(W2[(size_t)k*HID2 + col], W2[(size_t)(k+1)*HID2 + col]);
    }
  }
}

// ---------------- fused scan + G-prep ----------------
struct FusedP {
  // scan
  const float *path;
  const float *eW1,*eb1,*eg1,*ebt1,*eW2,*eb2,*eg2,*ebt2;
  const u32 *w1f, *w2f;
  const float *b1,*g1,*bt1,*b2,*g2,*bt2;
  const float *Wv,*bv,*Wo,*bo,*dW1,*db1,*dW2,*db2;
  const float *hb,*gb;
  const u32 *Gp;          // scan-consumed buffer
  float *zstate, *out;
  int s0, s1, do_enc, do_epi, scan_on;
  // prep
  const u32 *w3h, *dxh;
  u32 *Gpw;               // prep-written buffer
  int ps0, pcs;
};

__global__ __launch_bounds__(256, 1) void fused_kernel(FusedP p){
  const int tid = threadIdx.x;
  // scan shared
  __shared__ __align__(16) u16 zst_h[HID];
  __shared__ __align__(16) u16 a1p_h[HID2];
  __shared__ __align__(16) u16 a2p_h[HID2];
  __shared__ __align__(16) float red[8];
  __shared__ __align__(16) float zf[HID];
  __shared__ __align__(16) float sc1[HID2];
  // prep shared
  __shared__ u32 sdx[BB * 16];

  if (p.scan_on && blockIdx.x < BB){
    // ================= SCAN (R6 body + prio + chain-split) =================
    setprio_hi();
    const int b = blockIdx.x;
    const int lane = tid & 63, w = tid >> 6;
    const int quad = lane >> 4, n16 = lane & 15;
    const bool owner = (quad == 0);

    uint4 w1r[16], w2r[32];
    {
      const uint4* s1p = (const uint4*)p.w1f + ((size_t)(w*64 + lane))*16;
      #pragma unroll
      for (int i = 0; i < 16; ++i) w1r[i] = s1p[i];
      const uint4* s2p = (const uint4*)p.w2f + ((size_t)(w*64 + lane))*32;
      #pragma unroll
      for (int i = 0; i < 32; ++i) w2r[i] = s2p[i];
    }
    float rb1[4], rg1[4], rbt1[4], rb2[4], rg2[4], rbt2[4];
    #pragma unroll
    for (int nt = 0; nt < 4; ++nt){
      int col = w*64 + nt*16 + n16;
      rb1[nt] = p.b1[col]; rg1[nt] = p.g1[col]; rbt1[nt] = p.bt1[col];
      rb2[nt] = p.b2[col]; rg2[nt] = p.g2[col]; rbt2[nt] = p.bt2[col];
    }
    const int h0 = w*32 + n16, h1 = h0 + 16;

    float mu, sq;
    if (p.do_enc){
      if (tid < IND) sc1[tid] = p.path[(b*SS + 0)*IND + tid];
      __syncthreads();
      float acc = 0.f;
      if (tid < HID){
        acc = p.eb1[tid];
        #pragma unroll 8
        for (int i = 0; i < IND; ++i) acc = fmaf(sc1[i], p.eW1[i*HID + tid], acc);
      }
      float cx = (tid < HID) ? acc : 0.f;
      bsum2(cx, cx*cx, red, tid, mu, sq);
      mu *= (1.f/HID); float var = sq*(1.f/HID) - mu*mu; float rstd = rsqrtf(var + 1e-5f);
      if (tid < HID) zf[tid] = gelu_f((acc - mu)*rstd*p.eg1[tid] + p.ebt1[tid]);
      __syncthreads();
      float acc2 = 0.f;
      if (tid < HID){
        acc2 = p.eb2[tid];
        #pragma unroll 8
        for (int h = 0; h < HID; ++h) acc2 = fmaf(zf[h], p.eW2[h*HID + tid], acc2);
      }
      cx = (tid < HID) ? acc2 : 0.f;
      bsum2(cx, cx*cx, red, tid, mu, sq);
      mu *= (1.f/HID); float var2 = sq*(1.f/HID) - mu*mu; float rstd2 = rsqrtf(var2 + 1e-5f);
      __syncthreads();
      if (tid < HID) zf[tid] = (acc2 - mu)*rstd2*p.eg2[tid] + p.ebt2[tid];
      __syncthreads();
    }
    float zc0 = 0.f, zc1 = 0.f;
    if (owner){
      if (p.do_enc){ zc0 = zf[h0]; zc1 = zf[h1]; }
      else { zc0 = p.zstate[b*HID + h0]; zc1 = p.zstate[b*HID + h1]; }
    }

    for (int s = p.s0; s < p.s1; ++s){
      const float hbv = p.hb[b*NSTEP + s];
      uint4 gr[16];
      {
        const uint4* g4 = (const uint4*)(p.Gp + ((size_t)(s - p.s0)*BB + b)*16384 + (size_t)w*4096);
        #pragma unroll
        for (int m = 0; m < 16; ++m) gr[m] = g4[m*64 + lane];
      }
      float gb0 = 0.f, gb1 = 0.f;
      if (owner){
        gb0 = p.gb[(b*NSTEP + s)*HID + h0];
        gb1 = p.gb[(b*NSTEP + s)*HID + h1];
        zst_h[h0] = f2h(zc0); zst_h[h1] = f2h(zc1);
      }
      float ks0 = 0.f, ks1 = 0.f;
      __syncthreads();

      #pragma unroll 1
      for (int st = 0; st < 4; ++st){
        // layer1: zst(1x128) @ W1(128x256), 16 MFMA, 8 accumulators (chain 2)
        f32x4 D0a={0,0,0,0}, D1a={0,0,0,0}, D2a={0,0,0,0}, D3a={0,0,0,0};
        f32x4 D0b={0,0,0,0}, D1b={0,0,0,0}, D2b={0,0,0,0}, D3b={0,0,0,0};
        {
          const uint4* za = (const uint4*)zst_h;
          #pragma unroll
          for (int kt = 0; kt < 2; ++kt){
            f16x8 a; uint4 av = za[kt*4 + quad]; __builtin_memcpy(&a, &av, 16);
            f16x8 bf;
            __builtin_memcpy(&bf, &w1r[kt*4+0], 16); D0a = __builtin_amdgcn_mfma_f32_16x16x32_f16(a, bf, D0a, 0, 0, 0);
            __builtin_memcpy(&bf, &w1r[kt*4+1], 16); D1a = __builtin_amdgcn_mfma_f32_16x16x32_f16(a, bf, D1a, 0, 0, 0);
            __builtin_memcpy(&bf, &w1r[kt*4+2], 16); D2a = __builtin_amdgcn_mfma_f32_16x16x32_f16(a, bf, D2a, 0, 0, 0);
            __builtin_memcpy(&bf, &w1r[kt*4+3], 16); D3a = __builtin_amdgcn_mfma_f32_16x16x32_f16(a, bf, D3a, 0, 0, 0);
          }
          #pragma unroll
          for (int kt = 2; kt < 4; ++kt){
            f16x8 a; uint4 av = za[kt*4 + quad]; __builtin_memcpy(&a, &av, 16);
            f16x8 bf;
            __builtin_memcpy(&bf, &w1r[kt*4+0], 16); D0b = __builtin_amdgcn_mfma_f32_16x16x32_f16(a, bf, D0b, 0, 0, 0);
            __builtin_memcpy(&bf, &w1r[kt*4+1], 16); D1b = __builtin_amdgcn_mfma_f32_16x16x32_f16(a, bf, D1b, 0, 0, 0);
            __builtin_memcpy(&bf, &w1r[kt*4+2], 16); D2b = __builtin_amdgcn_mfma_f32_16x16x32_f16(a, bf, D2b, 0, 0, 0);
            __builtin_memcpy(&bf, &w1r[kt*4+3], 16); D3b = __builtin_amdgcn_mfma_f32_16x16x32_f16(a, bf, D3b, 0, 0, 0);
          }
        }
        float v0 = (D0a[0]+D0b[0]) + rb1[0], v1 = (D1a[0]+D1b[0]) + rb1[1];
        float v2 = (D2a[0]+D2b[0]) + rb1[2], v3 = (D3a[0]+D3b[0]) + rb1[3];
        float ssum = wred((v0 + v1) + (v2 + v3));
        float ssq  = wred((v0*v0 + v1*v1) + (v2*v2 + v3*v3));
        if (lane == 63){ red[w*2] = ssum; red[w*2+1] = ssq; }
        __syncthreads();                                    // b1
        {
          const float4* r4 = (const float4*)red;
          float4 ra = r4[0], rb = r4[1];
          float m1 = (ra.x + ra.z + rb.x + rb.z)*(1.f/1024.f);
          float q1 = (ra.y + ra.w + rb.y + rb.w)*(1.f/1024.f);
          float rs1 = rsqrtf(q1 - m1*m1 + 1e-5f);
          if (owner){
            a1p_h[w*64 +  0 + n16] = f2h(gelu_f((v0 - m1)*rs1*rg1[0] + rbt1[0]));
            a1p_h[w*64 + 16 + n16] = f2h(gelu_f((v1 - m1)*rs1*rg1[1] + rbt1[1]));
            a1p_h[w*64 + 32 + n16] = f2h(gelu_f((v2 - m1)*rs1*rg1[2] + rbt1[2]));
            a1p_h[w*64 + 48 + n16] = f2h(gelu_f((v3 - m1)*rs1*rg1[3] + rbt1[3]));
          }
        }
        __syncthreads();                                    // b2
        // layer2: a1(1x256) @ W2(256x256), 32 MFMA, 8 accumulators (chain 4)
        D0a={0,0,0,0}; D1a={0,0,0,0}; D2a={0,0,0,0}; D3a={0,0,0,0};
        D0b={0,0,0,0}; D1b={0,0,0,0}; D2b={0,0,0,0}; D3b={0,0,0,0};
        {
          const uint4* aa = (const uint4*)a1p_h;
          #pragma unroll
          for (int kt = 0; kt < 4; ++kt){
            f16x8 a; uint4 av = aa[kt*4 + quad]; __builtin_memcpy(&a, &av, 16);
            f16x8 bf;
            __builtin_memcpy(&bf, &w2r[kt*4+0], 16); D0a = __builtin_amdgcn_mfma_f32_16x16x32_f16(a, bf, D0a, 0, 0, 0);
            __builtin_memcpy(&bf, &w2r[kt*4+1], 16); D1a = __builtin_amdgcn_mfma_f32_16x16x32_f16(a, bf, D1a, 0, 0, 0);
            __builtin_memcpy(&bf, &w2r[kt*4+2], 16); D2a = __builtin_amdgcn_mfma_f32_16x16x32_f16(a, bf, D2a, 0, 0, 0);
            __builtin_memcpy(&bf, &w2r[kt*4+3], 16); D3a = __builtin_amdgcn_mfma_f32_16x16x32_f16(a, bf, D3a, 0, 0, 0);
          }
          #pragma unroll
          for (int kt = 4; kt < 8; ++kt){
            f16x8 a; uint4 av = aa[kt*4 + quad]; __builtin_memcpy(&a, &av, 16);
            f16x8 bf;
            __builtin_memcpy(&bf, &w2r[kt*4+0], 16); D0b = __builtin_amdgcn_mfma_f32_16x16x32_f16(a, bf, D0b, 0, 0, 0);
            __builtin_memcpy(&bf, &w2r[kt*4+1], 16); D1b = __builtin_amdgcn_mfma_f32_16x16x32_f16(a, bf, D1b, 0, 0, 0);
            __builtin_memcpy(&bf, &w2r[kt*4+2], 16); D2b = __builtin_amdgcn_mfma_f32_16x16x32_f16(a, bf, D2b, 0, 0, 0);
            __builtin_memcpy(&bf, &w2r[kt*4+3], 16); D3b = __builtin_amdgcn_mfma_f32_16x16x32_f16(a, bf, D3b, 0, 0, 0);
          }
        }
        v0 = (D0a[0]+D0b[0]) + rb2[0]; v1 = (D1a[0]+D1b[0]) + rb2[1];
        v2 = (D2a[0]+D2b[0]) + rb2[2]; v3 = (D3a[0]+D3b[0]) + rb2[3];
        ssum = wred((v0 + v1) + (v2 + v3));
        ssq  = wred((v0*v0 + v1*v1) + (v2*v2 + v3*v3));
        if (lane == 63){ red[w*2] = ssum; red[w*2+1] = ssq; }
        __syncthreads();                                    // b3
        {
          const float4* r4 = (const float4*)red;
          float4 ra = r4[0], rb = r4[1];
          float m2 = (ra.x + ra.z + rb.x + rb.z)*(1.f/1024.f);
          float q2 = (ra.y + ra.w + rb.y + rb.w)*(1.f/1024.f);
          float rs2 = rsqrtf(q2 - m2*m2 + 1e-5f);
          if (owner){
            a2p_h[w*64 +  0 + n16] = f2h(gelu_f((v0 - m2)*rs2*rg2[0] + rbt2[0]));
            a2p_h[w*64 + 16 + n16] = f2h(gelu_f((v1 - m2)*rs2*rg2[1] + rbt2[1]));
            a2p_h[w*64 + 32 + n16] = f2h(gelu_f((v2 - m2)*rs2*rg2[2] + rbt2[2]));
            a2p_h[w*64 + 48 + n16] = f2h(gelu_f((v3 - m2)*rs2*rg2[3] + rbt2[3]));
          }
        }
        __syncthreads();                                    // b4
        // layer3: a2(1x256) @ G(256x32 cols of this wave), 16 MFMA, 4 accumulators
        f32x4 E0={0,0,0,0}, E1={0,0,0,0}, E2={0,0,0,0}, E3={0,0,0,0};
        {
          const uint4* aa = (const uint4*)a2p_h;
          #pragma unroll
          for (int kt = 0; kt < 4; ++kt){
            f16x8 a; uint4 av = aa[kt*4 + quad]; __builtin_memcpy(&a, &av, 16);
            f16x8 g0f, g1f;
            __builtin_memcpy(&g0f, &gr[kt*2+0], 16);
            __builtin_memcpy(&g1f, &gr[kt*2+1], 16);
            E0 = __builtin_amdgcn_mfma_f32_16x16x32_f16(a, g0f, E0, 0, 0, 0);
            E1 = __builtin_amdgcn_mfma_f32_16x16x32_f16(a, g1f, E1, 0, 0, 0);
          }
          #pragma unroll
          for (int kt = 4; kt < 8; ++kt){
            f16x8 a; uint4 av = aa[kt*4 + quad]; __builtin_memcpy(&a, &av, 16);
            f16x8 g0f, g1f;
            __builtin_memcpy(&g0f, &gr[kt*2+0], 16);
            __builtin_memcpy(&g1f, &gr[kt*2+1], 16);
            E2 = __builtin_amdgcn_mfma_f32_16x16x32_f16(a, g0f, E2, 0, 0, 0);
            E3 = __builtin_amdgcn_mfma_f32_16x16x32_f16(a, g1f, E3, 0, 0, 0);
          }
        }
        if (owner){
          float kv0 = (E0[0] + E2[0]) + gb0, kv1 = (E1[0] + E3[0]) + gb1;
          float cst = (st == 0 || st == 3) ? 1.f : 2.f;
          ks0 += cst*kv0; ks1 += cst*kv1;
          if (st < 3){
            float c = (st == 2) ? hbv : 0.5f*hbv;
            zst_h[h0] = f2h(zc0 + c*kv0);
            zst_h[h1] = f2h(zc1 + c*kv1);
          }
        }
        __syncthreads();                                    // b5
      }
      if (owner){ zc0 += hbv*(1.f/6.f)*ks0; zc1 += hbv*(1.f/6.f)*ks1; }
    }

    if (p.do_epi){
      if (owner){ zf[h0] = zc0; zf[h1] = zc1; }
      __syncthreads();
      if (tid < HID){
        float v = p.bv[tid];
        #pragma unroll 8
        for (int h = 0; h < HID; ++h) v = fmaf(zf[h], p.Wv[h*HID + tid], v);
        sc1[tid] = v;
      }
      __syncthreads();
      if (tid < HID){
        float f = p.bo[tid];
        #pragma unroll 8
        for (int h = 0; h < HID; ++h) f = fmaf(sc1[h], p.Wo[h*HID + tid], f);
        sc1[HID + tid] = f;
      }
      __syncthreads();
      if (tid < HID){
        float hd = p.db1[tid];
        #pragma unroll 8
        for (int h = 0; h < HID; ++h) hd = fmaf(sc1[HID + h], p.dW1[h*HID + tid], hd);
        zf[tid] = gelu_f(hd);
      }
      __syncthreads();
      if (tid < 10){
        float t = p.db2[tid];
        #pragma unroll 8
        for (int h = 0; h < HID; ++h) t = fmaf(zf[h], p.dW2[h*10 + tid], t);
        p.out[b*10 + tid] = t;
      }
      if (tid == 0) p.out[BB*10 + b] = 1.0f;   // softmax over singleton axis == 1
    } else {
      if (owner){ p.zstate[b*HID + h0] = zc0; p.zstate[b*HID + h1] = zc1; }
    }
    return;
  }

  // ================= G-PREP (R6 body, low priority) =================
  {
    setprio_lo();
    const int pb = blockIdx.x - (p.scan_on ? BB : 0);
    const int sl = pb >> 6, xblk = pb & 63;
    if (sl >= p.pcs) return;
    const int s = p.ps0 + sl;
    const int lin = xblk*256 + tid;              // (kp, h)
    const int kp = lin >> 7, h = lin & 127;
    const uint4* wa = (const uint4*)(p.w3h + ((size_t)(2*kp)*HID + h)*16);
    const uint4* wb = (const uint4*)(p.w3h + ((size_t)(2*kp+1)*HID + h)*16);
    uint4 A0 = wa[0], A1 = wa[1], A2 = wa[2], A3 = wa[3];
    uint4 B0 = wb[0], B1 = wb[1], B2 = wb[2], B3 = wb[3];
    for (int t = tid; t < BB * 16; t += 256){
      int bb = t >> 4, i2 = t & 15;
      sdx[t] = p.dxh[((size_t)bb*NSTEP + s)*16 + i2];
    }
    __syncthreads();
    // fragment-layout output offset
    const int kt = kp >> 4, q = kp & 3, quad2 = (kp >> 2) & 3;
    const int wq = h >> 5, tq = (h >> 4) & 1, nn = h & 15;
    const size_t off = (size_t)wq*4096 + (size_t)(kt*2 + tq)*256 + (size_t)(quad2*16 + nn)*4 + q;
    const size_t base_sl = (size_t)sl * BB * 16384;
    u32* __restrict__ Gout = p.Gpw;
    for (int bb = 0; bb < BB; ++bb){
      const uint4* dp = (const uint4*)&sdx[bb*16];
      uint4 D0 = dp[0], D1 = dp[1], D2 = dp[2], D3 = dp[3];
      float g0 = 0.f, g1 = 0.f, g2 = 0.f, g3 = 0.f;
      g0 = dot2f(D0.x, A0.x, g0); g0 = dot2f(D0.y, A0.y, g0);
      g0 = dot2f(D0.z, A0.z, g0); g0 = dot2f(D0.w, A0.w, g0);
      g2 = dot2f(D1.x, A1.x, g2); g2 = dot2f(D1.y, A1.y, g2);
      g2 = dot2f(D1.z, A1.z, g2); g2 = dot2f(D1.w, A1.w, g2);
      g0 = dot2f(D2.x, A2.x, g0); g0 = dot2f(D2.y, A2.y, g0);
      g0 = dot2f(D2.z, A2.z, g0); g0 = dot2f(D2.w, A2.w, g0);
      g2 = dot2f(D3.x, A3.x, g2); g2 = dot2f(D3.y, A3.y, g2);
      g2 = dot2f(D3.z, A3.z, g2); g2 = dot2f(D3.w, A3.w, g2);
      g1 = dot2f(D0.x, B0.x, g1); g1 = dot2f(D0.y, B0.y, g1);
      g1 = dot2f(D0.z, B0.z, g1); g1 = dot2f(D0.w, B0.w, g1);
      g3 = dot2f(D1.x, B1.x, g3); g3 = dot2f(D1.y, B1.y, g3);
      g3 = dot2f(D1.z, B1.z, g3); g3 = dot2f(D1.w, B1.w, g3);
      g1 = dot2f(D2.x, B2.x, g1); g1 = dot2f(D2.y, B2.y, g1);
      g1 = dot2f(D2.z, B2.z, g1); g1 = dot2f(D2.w, B2.w, g1);
      g3 = dot2f(D3.x, B3.x, g3); g3 = dot2f(D3.y, B3.y, g3);
      g3 = dot2f(D3.z, B3.z, g3); g3 = dot2f(D3.w, B3.w, g3);
      Gout[base_sl + (size_t)bb*16384 + off] = pkh2(g0 + g2, g1 + g3);
    }
  }
}

extern "C" void kernel_launch(void* const* d_in, const int* in_sizes, int n_in,
                              void* d_out, int out_size, void* d_ws, size_t ws_size,
                              hipStream_t stream){
  const float* path  = (const float*)d_in[0];
  const float* ts    = (const float*)d_in[1];
  const float* eW1   = (const float*)d_in[2];
  const float* eb1   = (const float*)d_in[3];
  const float* eg1   = (const float*)d_in[4];
  const float* ebt1  = (const float*)d_in[5];
  const float* eW2   = (const float*)d_in[6];
  const float* eb2   = (const float*)d_in[7];
  const float* eg2   = (const float*)d_in[8];
  const float* ebt2  = (const float*)d_in[9];
  const float* vW1   = (const float*)d_in[10];
  const float* vb1   = (const float*)d_in[11];
  const float* vg1   = (const float*)d_in[12];
  const float* vbt1  = (const float*)d_in[13];
  const float* vW2   = (const float*)d_in[14];
  const float* vb2   = (const float*)d_in[15];
  const float* vg2   = (const float*)d_in[16];
  const float* vbt2  = (const float*)d_in[17];
  const float* vW3   = (const float*)d_in[18];
  const float* vb3   = (const float*)d_in[19];
  const float* Wv    = (const float*)d_in[24];
  const float* bv    = (const float*)d_in[25];
  const float* Wo    = (const float*)d_in[26];
  const float* bo    = (const float*)d_in[27];
  const float* dW1   = (const float*)d_in[28];
  const float* db1   = (const float*)d_in[29];
  const float* dW2   = (const float*)d_in[30];
  const float* db2   = (const float*)d_in[31];

  char* wsb = (char*)d_ws;
  float* z_state = (float*)(wsb + 0);              // 64 KB
  u32*   dxh = (u32*)(wsb + 65536);                // 248 KB
  float* hb  = (float*)(wsb + 319488);             // 16 KB
  float* gb  = (float*)(wsb + 335872);             // 1.94 MB
  u32*   w3h = (u32*)(wsb + 2367488);              // 2 MB
  u32*   w1f = (u32*)(wsb + 4464640);              // 64 KB
  u32*   w2f = (u32*)(wsb + 4530176);              // 128 KB
  const size_t gbase = 4661248;

  hipLaunchKernelGGL(setup_kernel, dim3(BB + 2048 + 192), dim3(256), 0, stream,
                     path, ts, vb3, vW3, vW1, vW2, dxh, hb, gb, w3h, w1f, w2f);

  const size_t per_step = (size_t)BB * 16384 * 4;  // 8 MB per step
  size_t avail = (ws_size > gbase) ? (ws_size - gbase) : 0;
  int pipelined, c;
  int capp = (int)((avail/2) / per_step);
  if (capp >= 2){
    pipelined = 1;
    c = capp < 8 ? capp : 8;
    if (c > NSTEP) c = NSTEP;
  } else {
    pipelined = 0;
    c = (int)(avail / per_step);
    if (c < 1) c = 1;
    if (c > NSTEP) c = NSTEP;
  }
  const int nch = (NSTEP + c - 1) / c;
  u32* GpA = (u32*)(wsb + gbase);
  u32* GpB = (u32*)(wsb + gbase + (size_t)c*per_step);

  FusedP base;
  base.path = path;
  base.eW1 = eW1; base.eb1 = eb1; base.eg1 = eg1; base.ebt1 = ebt1;
  base.eW2 = eW2; base.eb2 = eb2; base.eg2 = eg2; base.ebt2 = ebt2;
  base.w1f = w1f; base.w2f = w2f;
  base.b1 = vb1; base.g1 = vg1; base.bt1 = vbt1;
  base.b2 = vb2; base.g2 = vg2; base.bt2 = vbt2;
  base.Wv = Wv; base.bv = bv; base.Wo = Wo; base.bo = bo;
  base.dW1 = dW1; base.db1 = db1; base.dW2 = dW2; base.db2 = db2;
  base.hb = hb; base.gb = gb;
  base.zstate = z_state; base.out = (float*)d_out;
  base.w3h = w3h; base.dxh = dxh;
  base.Gp = GpA; base.Gpw = GpA;
  base.s0 = 0; base.s1 = 0; base.do_enc = 0; base.do_epi = 0; base.scan_on = 0;
  base.ps0 = 0; base.pcs = 0;

  if (pipelined){
    for (int i = 0; i <= nch; ++i){
      FusedP P = base;
      int scan_i = i - 1, prep_i = i;
      P.scan_on = (scan_i >= 0) ? 1 : 0;
      if (P.scan_on){
        P.s0 = scan_i*c;
        P.s1 = (P.s0 + c < NSTEP) ? (P.s0 + c) : NSTEP;
        P.Gp = (scan_i & 1) ? GpB : GpA;
        P.do_enc = (scan_i == 0) ? 1 : 0;
        P.do_epi = (P.s1 == NSTEP) ? 1 : 0;
      }
      if (prep_i < nch){
        P.ps0 = prep_i*c;
        P.pcs = (NSTEP - P.ps0 < c) ? (NSTEP - P.ps0) : c;
        P.Gpw = (prep_i & 1) ? GpB : GpA;
      } else {
        P.pcs = 0;
      }
      int grid = (P.scan_on ? BB : 0) + 64*P.pcs;
      if (grid == 0) continue;
      hipLaunchKernelGGL(fused_kernel, dim3(grid), dim3(256), 0, stream, P);
    }
  } else {
    for (int i = 0; i < nch; ++i){
      int s0 = i*c;
      int cs = (NSTEP - s0 < c) ? (NSTEP - s0) : c;
      FusedP P1 = base;                 // prep only
      P1.scan_on = 0; P1.ps0 = s0; P1.pcs = cs; P1.Gpw = GpA;
      hipLaunchKernelGGL(fused_kernel, dim3(64*cs), dim3(256), 0, stream, P1);
      FusedP P2 = base;                 // scan only
      P2.scan_on = 1; P2.pcs = 0;
      P2.s0 = s0; P2.s1 = s0 + cs; P2.Gp = GpA;
      P2.do_enc = (s0 == 0) ? 1 : 0;
      P2.do_epi = (s0 + cs == NSTEP) ? 1 : 0;
      hipLaunchKernelGGL(fused_kernel, dim3(BB), dim3(256), 0, stream, P2);
    }
  }
}